// Round 5
// baseline (513.136 us; speedup 1.0000x reference)
//
#include <hip/hip_runtime.h>
#include <stdint.h>
#include <stddef.h>

// CapsuleFC: B=64, N_IN=2048, D_IN=16, N_OUT=64, D_OUT=16
constexpr int B_ = 64, N_ = 2048, A_ = 16, M_ = 64, D_ = 16;
constexpr float SCALE_ = 0.25f;   // 1/sqrt(16)
constexpr float EPS_ = 1e-6f;

typedef float f32x4 __attribute__((ext_vector_type(4)));

#define GL16(g, l)                                                             \
  __builtin_amdgcn_global_load_lds((__attribute__((address_space(1))) void*)(g), \
                                   (__attribute__((address_space(3))) void*)(l), \
                                   16, 0, 0)

// counted vmcnt wait (literal) — never 0 inside the main loop (T4)
#define WV(n) asm volatile("s_waitcnt vmcnt(" #n ")" ::: "memory")
#define BAR() do {                        \
    asm volatile("" ::: "memory");        \
    __builtin_amdgcn_s_barrier();         \
    asm volatile("" ::: "memory");        \
    __builtin_amdgcn_sched_barrier(0);    \
  } while (0)

// grid: 4*nch blocks. block: 512 threads = 8 waves; wave wv owns b-pair
// (b0 = bg*16 + wv*2); lane l owns out-capsule m = l.
// Double-buffered 32KB half-slabs of w[n] (8 a-planes), depth-1 counted vmcnt.
// Per-thread state: v[2][16]+acc[2][16]+cv[2][16] = 96 floats -> fits 128 VGPR
// (R4's 4-b state spilled to scratch: WRITE_SIZE 626MB; this is the fix).
__global__ __launch_bounds__(512, 4) void caps_main(
    const float* __restrict__ input,   // [B,N,A]
    const float* __restrict__ cact,    // [B,N]
    const float* __restrict__ ncv,     // [B,M,D]
    const float* __restrict__ nact,    // [B,M]
    const float* __restrict__ w,       // [N,A,M,D]
    float* __restrict__ qk_out,        // [B,N,M]
    float* __restrict__ partial,       // [nch,B,M,D]
    int C, int nch)
{
  __shared__ __align__(128) char wl[2][32768];   // two a-half slabs

  const int tid  = threadIdx.x;
  const int lane = tid & 63;
  const int wv   = __builtin_amdgcn_readfirstlane(tid >> 6);

  // XCD co-location: the 4 bgroup-sharers of chunk ch share flat%8 -> same L2
  const int flat = blockIdx.x;
  int bg, ch;
  if (nch & 7) { bg = flat & 3; ch = flat >> 2; }
  else { const int x = flat & 7, r = flat >> 3; bg = r & 3; ch = (r >> 2) * 8 + x; }

  const int b0g = bg * 16;
  const int b0  = b0g + wv * 2;      // this wave's first b (owns b0, b0+1)
  const int n0  = ch * C;

  // swizzled LDS read offsets (pairs with stage-side source involution)
  int offj[4];
#pragma unroll
  for (int j = 0; j < 4; ++j)
    offj[j] = (lane * 64 + j * 16) ^ (((lane >> 1) & 7) << 4);

  // loop-invariant per-(b,m): issued BEFORE any staged load -> oldest in
  // vmcnt order -> force-completed by the first counted wait.
  float na[2], cv[2][16];
#pragma unroll
  for (int bi = 0; bi < 2; ++bi) {
    na[bi] = nact[(b0 + bi) * M_ + lane];
    const f32x4* np4 = (const f32x4*)(ncv + ((size_t)(b0 + bi) * M_ + lane) * D_);
#pragma unroll
    for (int j = 0; j < 4; ++j) {
      const f32x4 t = np4[j];
      cv[bi][4*j+0] = t.x; cv[bi][4*j+1] = t.y; cv[bi][4*j+2] = t.z; cv[bi][4*j+3] = t.w;
    }
  }

  float acc[2][16], v[2][16];
#pragma unroll
  for (int bi = 0; bi < 2; ++bi)
#pragma unroll
    for (int d = 0; d < 16; ++d) acc[bi][d] = 0.f;

  // stage half-step h: 32KB = a-half (h&1) of w[n0+h/2] into wl[h&1].
  // LDS dest linear; global SOURCE pre-swizzled (involution bits[6:4]^=bits[9:7]).
  auto STAGE = [&](int h) {
    const int n = n0 + (h >> 1);
    const char* ws = (const char*)w + ((size_t)n << 16) + ((size_t)(h & 1) << 15);
    char* lb = (char*)wl[h & 1] + wv * 1024;
#pragma unroll
    for (int i = 0; i < 4; ++i) {
      const uint32_t P = (uint32_t)(i * 8192 + tid * 16);
      const uint32_t S = P ^ (((P >> 7) & 7u) << 4);
      GL16(ws + S, lb + i * 8192);
    }
  };

  auto COMPUTE = [&](int h) {
    const int n  = n0 + (h >> 1);
    const int ah = h & 1;
    const char* lb = (const char*)wl[ah];
    if (ah == 0) {
#pragma unroll
      for (int bi = 0; bi < 2; ++bi)
#pragma unroll
        for (int d = 0; d < 16; ++d) v[bi][d] = 0.f;
    }
    // input half-rows: uniform (per-wave) -> s_load, lgkmcnt not vmcnt
    float ib[2][8];
#pragma unroll
    for (int bi = 0; bi < 2; ++bi) {
      const int ibase = __builtin_amdgcn_readfirstlane(
          ((b0 + bi) * N_ + n) * A_ + ah * 8);
      const f32x4 r0 = *(const f32x4*)(input + ibase);
      const f32x4 r1 = *(const f32x4*)(input + ibase + 4);
      ib[bi][0] = r0.x; ib[bi][1] = r0.y; ib[bi][2] = r0.z; ib[bi][3] = r0.w;
      ib[bi][4] = r1.x; ib[bi][5] = r1.y; ib[bi][6] = r1.z; ib[bi][7] = r1.w;
    }
#pragma unroll
    for (int al = 0; al < 8; ++al) {
      f32x4 wr[4];
#pragma unroll
      for (int j = 0; j < 4; ++j)
        wr[j] = *(const f32x4*)(lb + al * 4096 + offj[j]);
#pragma unroll
      for (int bi = 0; bi < 2; ++bi) {
        const float x = ib[bi][al];
#pragma unroll
        for (int j = 0; j < 4; ++j) {
          v[bi][4*j+0] += x * wr[j].x; v[bi][4*j+1] += x * wr[j].y;
          v[bi][4*j+2] += x * wr[j].z; v[bi][4*j+3] += x * wr[j].w;
        }
      }
    }
    if (ah == 1) {
#pragma unroll
      for (int bi = 0; bi < 2; ++bi) {
        float s = 0.f;
#pragma unroll
        for (int d = 0; d < 16; ++d) s += v[bi][d] * cv[bi][d];
        s *= SCALE_;
        // |s| small (s ~ N(0,~0.2)); max-sub cancels in the ratio -> skip.
        const float e = __expf(s);
        const float ena = e * na[bi];
        float Ps = ena;
#pragma unroll
        for (int off = 32; off >= 1; off >>= 1) Ps += __shfl_xor(Ps, off, 64);
        const float qk = ena / Ps;   // 1e-10 terms ~2e-10 rel: dropped
        qk_out[((size_t)(b0 + bi) * N_ + n) * M_ + lane] = qk;
        float ab = cact[__builtin_amdgcn_readfirstlane((b0 + bi) * N_ + n)];
        ab = fminf(fmaxf(ab, EPS_), 1.0f - EPS_);
        const float wq = qk * ab;
#pragma unroll
        for (int d = 0; d < 16; ++d) acc[bi][d] += wq * v[bi][d];
      }
    }
  };

  const int HT = 2 * C;
  STAGE(0);
  for (int h = 0; h < HT - 1; ++h) {
    STAGE(h + 1);
    // wait for stage(h); younger ops kept in flight: stage(h+1) = 4 loads,
    // plus 2 qk stores when COMPUTE(h-1) was an odd half (h even, h>0).
    if (h == 0 || (h & 1)) WV(4); else WV(6);
    BAR();               // all waves' stage(h) portions landed
    COMPUTE(h);
    BAR();               // all waves done reading wl[h&1] before restage
  }
  WV(0);
  BAR();
  COMPUTE(HT - 1);

  // partial[ch][b][m][d]
#pragma unroll
  for (int bi = 0; bi < 2; ++bi) {
    float* pp = partial + (((size_t)ch * B_ + (b0 + bi)) * M_ + lane) * D_;
#pragma unroll
    for (int j = 0; j < 4; ++j) {
      f32x4 t;
      t.x = acc[bi][4*j+0]; t.y = acc[bi][4*j+1];
      t.z = acc[bi][4*j+2]; t.w = acc[bi][4*j+3];
      __builtin_nontemporal_store(t, (f32x4*)pp + j);
    }
  }
}

__global__ void caps_reduce(const float* __restrict__ part,
                            const float* __restrict__ nain,
                            float* __restrict__ out, int nch)
{
  const int i = blockIdx.x * 256 + threadIdx.x;  // one thread per out[b,m,d]
  float s = 0.f;
  for (int c = 0; c < nch; ++c) s += part[(size_t)c * (B_ * M_ * D_) + i];
  out[i] = s;
  if (i < B_ * M_) out[B_ * M_ * D_ + i] = nain[i];  // next_act passthrough
}

extern "C" void kernel_launch(void* const* d_in, const int* in_sizes, int n_in,
                              void* d_out, int out_size, void* d_ws, size_t ws_size,
                              hipStream_t stream)
{
  const float* input = (const float*)d_in[0];
  const float* cact  = (const float*)d_in[1];
  const float* ncv   = (const float*)d_in[2];
  const float* nact  = (const float*)d_in[3];
  const float* w     = (const float*)d_in[4];

  float* out     = (float*)d_out;
  float* qk_out  = out + (B_ * M_ * D_) + (B_ * M_);   // after out and next_act
  float* partial = (float*)d_ws;

  int nch = 128;  // power of two; 2MB of ws
  while ((size_t)nch * (size_t)(B_ * M_ * D_) * sizeof(float) > ws_size && nch > 32) nch >>= 1;
  const int C = N_ / nch;

  hipLaunchKernelGGL(caps_main, dim3(4 * nch), dim3(512), 0, stream,
                     input, cact, ncv, nact, w, qk_out, partial, C, nch);
  hipLaunchKernelGGL(caps_reduce, dim3(B_ * M_ * D_ / 256), dim3(256), 0, stream,
                     partial, nact, out, nch);
}

// Round 6
// 194.689 us; speedup vs baseline: 2.6357x; 2.6357x over previous
//
#include <hip/hip_runtime.h>
#include <stdint.h>
#include <stddef.h>

// CapsuleFC: B=64, N_IN=2048, D_IN=16, N_OUT=64, D_OUT=16
constexpr int B_ = 64, N_ = 2048, A_ = 16, M_ = 64, D_ = 16;
constexpr float SCALE_ = 0.25f;   // 1/sqrt(16)
constexpr float EPS_ = 1e-6f;

typedef float f32x4 __attribute__((ext_vector_type(4)));

#define GL16(g, l)                                                             \
  __builtin_amdgcn_global_load_lds((__attribute__((address_space(1))) void*)(g), \
                                   (__attribute__((address_space(3))) void*)(l), \
                                   16, 0, 0)

// grid: 4*nch blocks. block: 256 threads = 4 waves; wave wv owns 4 batches
// (b0 = bg*16 + wv*4); lane l owns out-capsule m = l.
// SIMPLE schedule: single-buffered 64KB w slab, plain __syncthreads.
// 2 blocks/CU (LDS 2x64KB) provide cross-block stage/compute overlap (m114).
// Register budget is the whole game (R3-R5 all spilled): persistent state =
// acc[4][16]+cv[4][16]+na = 132 fl, peak ~235 -> need the 256-VGPR class.
// waves_per_eu(2,2) pins 2 waves/SIMD: cap 256 VGPR, no spill-for-occupancy.
__global__ __launch_bounds__(256) __attribute__((amdgpu_waves_per_eu(2, 2)))
void caps_main(
    const float* __restrict__ input,   // [B,N,A]
    const float* __restrict__ cact,    // [B,N]
    const float* __restrict__ ncv,     // [B,M,D]
    const float* __restrict__ nact,    // [B,M]
    const float* __restrict__ w,       // [N,A,M,D]
    float* __restrict__ qk_out,        // [B,N,M]
    float* __restrict__ partial,       // [nch,B,M,D]
    int C, int nch)
{
  __shared__ __align__(128) char wl[65536];   // one w[n] slab (swizzled)

  const int tid  = threadIdx.x;
  const int lane = tid & 63;
  const int wv   = __builtin_amdgcn_readfirstlane(tid >> 6);

  // co-XCD mapping: the 4 bgroup-sharers of chunk ch land on xcd = ch&7
  const int flat = blockIdx.x;
  int bg, ch;
  if (nch & 7) { bg = flat & 3; ch = flat >> 2; }
  else { bg = (flat >> 3) & 3; ch = ((flat >> 5) << 3) | (flat & 7); }

  const int b0 = bg * 16 + wv * 4;
  const int n0 = ch * C;

  // swizzled LDS read offsets (pairs with the stage-side source involution:
  // bits[6:4] ^= bits[9:7]; per 8 lanes this spreads b128 reads over all
  // 8 16B slots of a 128B beat -> conflict-free)
  int offj[4];
#pragma unroll
  for (int j = 0; j < 4; ++j)
    offj[j] = (lane * 64 + j * 16) ^ (((lane >> 1) & 7) << 4);

  // loop-invariant per-(b,m) values in registers
  float na[4], cv[4][16];
#pragma unroll
  for (int bi = 0; bi < 4; ++bi) {
    na[bi] = nact[(b0 + bi) * M_ + lane];
    const f32x4* np4 = (const f32x4*)(ncv + ((size_t)(b0 + bi) * M_ + lane) * D_);
#pragma unroll
    for (int j = 0; j < 4; ++j) {
      const f32x4 t = np4[j];
      cv[bi][4*j+0] = t.x; cv[bi][4*j+1] = t.y;
      cv[bi][4*j+2] = t.z; cv[bi][4*j+3] = t.w;
    }
  }

  float acc[4][16];
#pragma unroll
  for (int bi = 0; bi < 4; ++bi)
#pragma unroll
    for (int d = 0; d < 16; ++d) acc[bi][d] = 0.f;

  for (int k = 0; k < C; ++k) {
    const int n = n0 + k;

    // ---- stage w[n] (64KB): source pre-swizzled, LDS dest linear
    {
      const char* ws = (const char*)w + ((size_t)n << 16);
#pragma unroll
      for (int i = 0; i < 16; ++i) {
        const uint32_t P = (uint32_t)(i * 4096 + tid * 16);
        const uint32_t S = P ^ (((P >> 7) & 7u) << 4);
        GL16(ws + S, (char*)wl + i * 4096 + wv * 1024);
      }
    }
    __syncthreads();   // drains vmcnt: slab ready

    // ---- votes: v[bi][d] = sum_a input[b,n,a] * w[n,a,m=lane,d]
    float v[4][16];
#pragma unroll
    for (int bi = 0; bi < 4; ++bi)
#pragma unroll
      for (int d = 0; d < 16; ++d) v[bi][d] = 0.f;

    int ibase[4];
#pragma unroll
    for (int bi = 0; bi < 4; ++bi)
      ibase[bi] = __builtin_amdgcn_readfirstlane(((b0 + bi) * N_ + n) * A_);

#pragma unroll
    for (int a = 0; a < 16; ++a) {
      f32x4 wr[4];
#pragma unroll
      for (int j = 0; j < 4; ++j)
        wr[j] = *(const f32x4*)((const char*)wl + a * 4096 + offj[j]);
#pragma unroll
      for (int bi = 0; bi < 4; ++bi) {
        const float x = input[ibase[bi] + a];   // wave-uniform -> s_load
#pragma unroll
        for (int j = 0; j < 4; ++j) {
          v[bi][4*j+0] += x * wr[j].x; v[bi][4*j+1] += x * wr[j].y;
          v[bi][4*j+2] += x * wr[j].z; v[bi][4*j+3] += x * wr[j].w;
        }
      }
    }

    // ---- scores -> wave-local softmax (m = lane) -> qk -> accumulate
#pragma unroll
    for (int bi = 0; bi < 4; ++bi) {
      float s = 0.f;
#pragma unroll
      for (int d = 0; d < 16; ++d) s += v[bi][d] * cv[bi][d];
      s *= SCALE_;
      // |s| small (~N(0,0.2)); max-subtraction cancels in the ratio -> skip
      const float e = __expf(s);
      const float ena = e * na[bi];
      float Ps = ena;
#pragma unroll
      for (int off = 32; off >= 1; off >>= 1) Ps += __shfl_xor(Ps, off, 64);
      const float qk = ena / Ps;   // 1e-10 terms ~2e-10 relative: dropped
      qk_out[((size_t)(b0 + bi) * N_ + n) * M_ + lane] = qk;
      float ab = cact[__builtin_amdgcn_readfirstlane((b0 + bi) * N_ + n)];
      ab = fminf(fmaxf(ab, EPS_), 1.0f - EPS_);
      const float wq = qk * ab;
#pragma unroll
      for (int d = 0; d < 16; ++d) acc[bi][d] += wq * v[bi][d];
    }

    __syncthreads();   // all waves done reading slab before restage
  }

  // partial[ch][b][m][d]
#pragma unroll
  for (int bi = 0; bi < 4; ++bi) {
    float* pp = partial + (((size_t)ch * B_ + (b0 + bi)) * M_ + lane) * D_;
#pragma unroll
    for (int j = 0; j < 4; ++j) {
      f32x4 t;
      t.x = acc[bi][4*j+0]; t.y = acc[bi][4*j+1];
      t.z = acc[bi][4*j+2]; t.w = acc[bi][4*j+3];
      __builtin_nontemporal_store(t, (f32x4*)pp + j);
    }
  }
}

__global__ void caps_reduce(const float* __restrict__ part,
                            const float* __restrict__ nain,
                            float* __restrict__ out, int nch)
{
  const int i = blockIdx.x * 256 + threadIdx.x;  // one thread per out[b,m,d]
  float s = 0.f;
  for (int c = 0; c < nch; ++c) s += part[(size_t)c * (B_ * M_ * D_) + i];
  out[i] = s;
  if (i < B_ * M_) out[B_ * M_ * D_ + i] = nain[i];  // next_act passthrough
}

extern "C" void kernel_launch(void* const* d_in, const int* in_sizes, int n_in,
                              void* d_out, int out_size, void* d_ws, size_t ws_size,
                              hipStream_t stream)
{
  const float* input = (const float*)d_in[0];
  const float* cact  = (const float*)d_in[1];
  const float* ncv   = (const float*)d_in[2];
  const float* nact  = (const float*)d_in[3];
  const float* w     = (const float*)d_in[4];

  float* out     = (float*)d_out;
  float* qk_out  = out + (B_ * M_ * D_) + (B_ * M_);   // after out and next_act
  float* partial = (float*)d_ws;

  int nch = 128;  // 512 blocks = 2/CU; 33.5MB of ws
  while ((size_t)nch * (size_t)(B_ * M_ * D_) * sizeof(float) > ws_size && nch > 8) nch >>= 1;
  const int C = N_ / nch;

  hipLaunchKernelGGL(caps_main, dim3(4 * nch), dim3(256), 0, stream,
                     input, cact, ncv, nact, w, qk_out, partial, C, nch);
  hipLaunchKernelGGL(caps_reduce, dim3(B_ * M_ * D_ / 256), dim3(256), 0, stream,
                     partial, nact, out, nch);
}